// Round 12
// baseline (195.625 us; speedup 1.0000x reference)
//
#include <hip/hip_runtime.h>
#include <math.h>

#define NN 50000
#define NE 800000
#define DF 128
#define NC 16
#define NSL 8              // feature slices (16 feats each); slice s -> XCD s
#define SW 16              // feats per slice
#define WLD 136            // padded LDS row stride (bf16 elems)
#define NBIN 196           // buckets: bin = dst>>8 (256 nodes per bucket)
#define EPB 8192           // edges per hist/scatter block
#define HB ((NE + EPB - 1) / EPB)      // 98 hist blocks
#define HL (NBIN * HB)                 // 19208 h entries
#define PB ((HL + 255) / 256)          // 76 scan blocks
#define GB ((NN + 63) / 64)            // 782 gemm1 blocks

typedef __bf16 bf16x8 __attribute__((ext_vector_type(8)));
typedef __bf16 bf16x4 __attribute__((ext_vector_type(4)));
typedef float  f32x4  __attribute__((ext_vector_type(4)));

// ---------------- prep: W1->W1T bf16 [128][128], W2->W2T bf16 [16][128] -----
__global__ void k_prep(const float* __restrict__ W1, const float* __restrict__ W2,
                       __bf16* __restrict__ W1T, __bf16* __restrict__ W2T) {
    int i = blockIdx.x * blockDim.x + threadIdx.x;
    if (i < DF * DF) {
        int n = i >> 7, k = i & 127;
        W1T[i] = (__bf16)W1[k * DF + n];
    }
    int j = i - DF * DF;
    if (j >= 0 && j < NC * DF) {
        int n = j >> 7, k = j & 127;
        W2T[j] = (__bf16)W2[k * NC + n];
    }
}

// ---------------- fused: [0,GB) gemm1 (MFMA, LDS W) | [GB,GB+HB) histogram --
// gemm1 writes H1 SLICE-MAJOR: H1s[s][node][16] with s = feat>>4
__global__ __launch_bounds__(256) void k_gemm1_hist(const float* __restrict__ X,
                                                    const __bf16* __restrict__ W1T,
                                                    __bf16* __restrict__ H1s,
                                                    const int* __restrict__ dst,
                                                    int* __restrict__ h) {
    __shared__ __bf16 wlds[DF * WLD];   // 34 KB
    __shared__ int hc[NBIN];
    if (blockIdx.x >= GB) {
        const int bb = blockIdx.x - GB;
        const int t = threadIdx.x;
        if (t < NBIN) hc[t] = 0;
        __syncthreads();
        const int base = bb * EPB;
#pragma unroll
        for (int i = 0; i < EPB / 256; ++i) {
            int e = base + i * 256 + t;
            if (e < NE) atomicAdd(&hc[dst[e] >> 8], 1);
        }
        __syncthreads();
        if (t < NBIN) h[t * HB + bb] = hc[t];   // bin-major
        return;
    }
    const int wid = threadIdx.x >> 6, lane = threadIdx.x & 63;
    const int m0 = blockIdx.x * 64 + wid * 16;
    const int m = m0 + (lane & 15);
    const int mc = (m < NN) ? m : NN - 1;
    const int l15 = lane & 15;
    const int kb = (lane >> 4) * 8;

    float4 xf[8];
#pragma unroll
    for (int q = 0; q < 4; ++q) {
        xf[2 * q]     = *(const float4*)&X[(size_t)mc * DF + q * 32 + kb];
        xf[2 * q + 1] = *(const float4*)&X[(size_t)mc * DF + q * 32 + kb + 4];
    }
    for (int i = threadIdx.x; i < DF * 16; i += 256) {
        int row = i >> 4, c8 = i & 15;
        *(bf16x8*)&wlds[row * WLD + c8 * 8] = ((const bf16x8*)W1T)[i];
    }
    __syncthreads();

    f32x4 acc[8];
#pragma unroll
    for (int nf = 0; nf < 8; ++nf) acc[nf] = (f32x4){0.f, 0.f, 0.f, 0.f};
#pragma unroll
    for (int ks = 0; ks < 4; ++ks) {
        float4 x0 = xf[2 * ks], x1 = xf[2 * ks + 1];
        bf16x8 xa;
        xa[0] = (__bf16)x0.x; xa[1] = (__bf16)x0.y; xa[2] = (__bf16)x0.z; xa[3] = (__bf16)x0.w;
        xa[4] = (__bf16)x1.x; xa[5] = (__bf16)x1.y; xa[6] = (__bf16)x1.z; xa[7] = (__bf16)x1.w;
#pragma unroll
        for (int nf = 0; nf < 8; ++nf) {
            bf16x8 wa = *(const bf16x8*)&wlds[(nf * 16 + l15) * WLD + ks * 32 + kb];
            acc[nf] = __builtin_amdgcn_mfma_f32_16x16x32_bf16(wa, xa, acc[nf], 0, 0, 0);
        }
    }
    if (m < NN) {
#pragma unroll
        for (int nf = 0; nf < 8; ++nf) {   // nf == slice index
            bf16x4 o;
            o[0] = (__bf16)acc[nf][0]; o[1] = (__bf16)acc[nf][1];
            o[2] = (__bf16)acc[nf][2]; o[3] = (__bf16)acc[nf][3];
            *(bf16x4*)&H1s[(size_t)nf * NN * SW + (size_t)m * SW + (lane >> 4) * 4] = o;
        }
    }
}

// ---------------- scan phase 1: per-block partial sums of h ----------------
__global__ __launch_bounds__(256) void k_hpart(const int* __restrict__ h,
                                               int* __restrict__ part) {
    __shared__ int ws[4];
    const int b = blockIdx.x, t = threadIdx.x;
    const int idx = b * 256 + t;
    int s = (idx < HL) ? h[idx] : 0;
    for (int o = 32; o > 0; o >>= 1) s += __shfl_down(s, o);
    if ((t & 63) == 0) ws[t >> 6] = s;
    __syncthreads();
    if (t == 0) part[b] = ws[0] + ws[1] + ws[2] + ws[3];
}

// ---------------- scan phase 2: scan PB partials (single block) -------------
__global__ __launch_bounds__(256) void k_hscan_part(const int* __restrict__ part,
                                                    int* __restrict__ partoff,
                                                    int* __restrict__ hscan) {
    __shared__ int s[256];
    const int t = threadIdx.x;
    int v = (t < PB) ? part[t] : 0;
    s[t] = v;
    __syncthreads();
    for (int o = 1; o < 256; o <<= 1) {
        int x = (t >= o) ? s[t - o] : 0;
        __syncthreads();
        s[t] += x;
        __syncthreads();
    }
    if (t < PB) partoff[t] = s[t] - v;       // exclusive
    if (t == 255) hscan[HL] = s[255];        // sentinel = NE
}

// ---------------- scan phase 3: block-local scan -> hscan -------------------
__global__ __launch_bounds__(256) void k_hoff(const int* __restrict__ h,
                                              const int* __restrict__ partoff,
                                              int* __restrict__ hscan) {
    __shared__ int s[256];
    const int b = blockIdx.x, t = threadIdx.x;
    const int idx = b * 256 + t;
    int v = (idx < HL) ? h[idx] : 0;
    s[t] = v;
    __syncthreads();
    for (int o = 1; o < 256; o <<= 1) {
        int x = (t >= o) ? s[t - o] : 0;
        __syncthreads();
        s[t] += x;
        __syncthreads();
    }
    if (idx < HL) hscan[idx] = partoff[b] + s[t] - v;
}

// ---------------- scatter into buckets (packed: (dst&255)<<16 | src) --------
__global__ __launch_bounds__(256) void k_scatterA(const int* __restrict__ src,
                                                  const int* __restrict__ dst,
                                                  const int* __restrict__ hscan,
                                                  int* __restrict__ ebuf) {
    __shared__ int cur[NBIN];
    const int bb = blockIdx.x, t = threadIdx.x;
    if (t < NBIN) cur[t] = hscan[t * HB + bb];
    __syncthreads();
    const int base = bb * EPB;
#pragma unroll
    for (int i = 0; i < EPB / 256; ++i) {
        int e = base + i * 256 + t;
        if (e < NE) {
            int s = src[e], d = dst[e];
            int pos = atomicAdd(&cur[d >> 8], 1);
            ebuf[pos] = s | ((d & 255) << 16);
        }
    }
}

// ---------------- per-bucket rank: off, dis, rec[src] (ushort) --------------
__global__ __launch_bounds__(256) void k_rankB(const int* __restrict__ ebuf,
                                               const int* __restrict__ hscan,
                                               int* __restrict__ off,
                                               float* __restrict__ dis,
                                               unsigned short* __restrict__ rec) {
    __shared__ int cnt[256], s[256], cur[256];
    const int bin = blockIdx.x, t = threadIdx.x;
    const int base = hscan[bin * HB];
    const int end  = hscan[(bin + 1) * HB];   // bin+1==NBIN -> sentinel = NE
    cnt[t] = 0;
    __syncthreads();
    for (int e = base + t; e < end; e += 256)
        atomicAdd(&cnt[(ebuf[e] >> 16) & 255], 1);
    __syncthreads();
    int c = cnt[t];
    s[t] = c;
    __syncthreads();
    for (int o = 1; o < 256; o <<= 1) {
        int x = (t >= o) ? s[t - o] : 0;
        __syncthreads();
        s[t] += x;
        __syncthreads();
    }
    int lo = s[t] - c;                         // exclusive within bucket
    int d = (bin << 8) + t;
    if (d < NN) {
        off[d] = base + lo;
        dis[d] = rsqrtf((float)(c + 1));       // +1 self-loop
    }
    if (bin == NBIN - 1 && t == 0) off[NN] = NE;
    cur[t] = base + lo;
    __syncthreads();
    for (int e = base + t; e < end; e += 256) {
        int ed = ebuf[e];
        int p = atomicAdd(&cur[(ed >> 16) & 255], 1);
        rec[p] = (unsigned short)(ed & 0xFFFF);
    }
}

// ---------------- sliced edge-sum gather: slice s = blockIdx%8 (XCD-pinned) -
// wave per node; 16 edges in flight (4 lanes/edge, 8B each); bf16 out
__global__ __launch_bounds__(256) void k_aggS(const __bf16* __restrict__ H1s,
                                              const float* __restrict__ dis,
                                              const int* __restrict__ off,
                                              const unsigned short* __restrict__ rec,
                                              __bf16* __restrict__ AGGs) {
    const int s = blockIdx.x & (NSL - 1);
    const int chunk = blockIdx.x >> 3;
    const int wid = threadIdx.x >> 6, lane = threadIdx.x & 63;
    const int n = chunk * 4 + wid;          // < 50000 by construction
    const int eg = lane >> 2;               // edge group 0..15
    const int fl = lane & 3;                // feat chunk 0..3 (4 feats)
    const __bf16* Hs = H1s + (size_t)s * NN * SW;

    float a[4] = {0.f, 0.f, 0.f, 0.f};
    const int e0 = off[n], e1 = off[n + 1];
    for (int eb = e0; eb < e1; eb += 16) {
        int e = eb + eg;
        bool ok = e < e1;
        int r = rec[ok ? e : eb];
        float w = ok ? dis[r] : 0.f;
        bf16x4 hv = *(const bf16x4*)&Hs[(size_t)r * SW + fl * 4];
#pragma unroll
        for (int i = 0; i < 4; ++i) a[i] += (float)hv[i] * w;
    }
#pragma unroll
    for (int i = 0; i < 4; ++i) {
        a[i] += __shfl_xor(a[i], 4);
        a[i] += __shfl_xor(a[i], 8);
        a[i] += __shfl_xor(a[i], 16);
        a[i] += __shfl_xor(a[i], 32);
    }
    if (lane < 4) {
        bf16x4 o;
        o[0] = (__bf16)a[0]; o[1] = (__bf16)a[1];
        o[2] = (__bf16)a[2]; o[3] = (__bf16)a[3];
        *(bf16x4*)&AGGs[(size_t)s * NN * SW + (size_t)n * SW + fl * 4] = o;
    }
}

// ---------------- finalize: relu(aggs*dn + self*dn^2 + b1) -> mini-GEMM -> H2
__global__ __launch_bounds__(256) void k_fin(const __bf16* __restrict__ H1s,
                                             const __bf16* __restrict__ AGGs,
                                             const float* __restrict__ dis,
                                             const float* __restrict__ b1,
                                             const __bf16* __restrict__ W2T,
                                             float* __restrict__ H2) {
    const int wid = threadIdx.x >> 6, lane = threadIdx.x & 63;
    const int n = blockIdx.x * 4 + wid;
    if (n >= NN) return;
    const int g = lane >> 4, l16 = lane & 15;
    const int fo = l16 * 8;                      // feats l16*8 .. +7
    const float dn = dis[n], d2 = dn * dn;
    // slice-major read reproducing fo: slice = l16>>1, within = (l16&1)*8
    const size_t soff = (size_t)(l16 >> 1) * NN * SW + (size_t)n * SW + (l16 & 1) * 8;

    bf16x8 ag = *(const bf16x8*)&AGGs[soff];
    bf16x8 hs = *(const bf16x8*)&H1s[soff];
    float4 b0 = *(const float4*)&b1[fo];
    float4 b4 = *(const float4*)&b1[fo + 4];

    float a[8];
    a[0] = fmaxf((float)ag[0] * dn + (float)hs[0] * d2 + b0.x, 0.f);
    a[1] = fmaxf((float)ag[1] * dn + (float)hs[1] * d2 + b0.y, 0.f);
    a[2] = fmaxf((float)ag[2] * dn + (float)hs[2] * d2 + b0.z, 0.f);
    a[3] = fmaxf((float)ag[3] * dn + (float)hs[3] * d2 + b0.w, 0.f);
    a[4] = fmaxf((float)ag[4] * dn + (float)hs[4] * d2 + b4.x, 0.f);
    a[5] = fmaxf((float)ag[5] * dn + (float)hs[5] * d2 + b4.y, 0.f);
    a[6] = fmaxf((float)ag[6] * dn + (float)hs[6] * d2 + b4.z, 0.f);
    a[7] = fmaxf((float)ag[7] * dn + (float)hs[7] * d2 + b4.w, 0.f);

    float p[4];
#pragma unroll
    for (int j = 0; j < 4; ++j) {
        bf16x8 wr = *(const bf16x8*)&W2T[(size_t)(g * 4 + j) * DF + fo];
        float sum = 0.f;
#pragma unroll
        for (int i = 0; i < 8; ++i) sum += a[i] * (float)wr[i];
        p[j] = sum;
    }
#pragma unroll
    for (int o = 1; o <= 8; o <<= 1) {
#pragma unroll
        for (int j = 0; j < 4; ++j) p[j] += __shfl_xor(p[j], o);
    }
    if (l16 == 0) {
        f32x4 o4 = {p[0], p[1], p[2], p[3]};
        *(f32x4*)&H2[(size_t)n * NC + g * 4] = o4;
    }
}

// ---------------- agg layer 2: unroll-2, fused sigmoid -> OUT ---------------
__global__ __launch_bounds__(256) void k_agg2(const float* __restrict__ H2,
                                              const float* __restrict__ dis,
                                              const float* __restrict__ b2,
                                              const int* __restrict__ off,
                                              const unsigned short* __restrict__ rec,
                                              float* __restrict__ OUT) {
    const int wid = threadIdx.x >> 6, lane = threadIdx.x & 63;
    const int n = blockIdx.x * 4 + wid;
    if (n >= NN) return;
    const float dn = dis[n];

    const int g = lane >> 3, l8 = lane & 7;
    float ax = 0.f, ay = 0.f;
    const int e0 = off[n], e1 = off[n + 1];
    int e = e0 + g;
    for (; e + 8 < e1; e += 16) {
        int r0 = rec[e];
        int r1 = rec[e + 8];
        float w0 = dis[r0], w1 = dis[r1];
        float2 h0 = *(const float2*)&H2[(size_t)r0 * NC + l8 * 2];
        float2 h1 = *(const float2*)&H2[(size_t)r1 * NC + l8 * 2];
        ax += h0.x * w0;
        ay += h0.y * w0;
        ax += h1.x * w1;
        ay += h1.y * w1;
    }
    for (; e < e1; e += 8) {
        int r = rec[e];
        float w = dis[r];
        float2 h = *(const float2*)&H2[(size_t)r * NC + l8 * 2];
        ax += h.x * w;
        ay += h.y * w;
    }
    ax += __shfl_xor(ax, 8);  ay += __shfl_xor(ay, 8);
    ax += __shfl_xor(ax, 16); ay += __shfl_xor(ay, 16);
    ax += __shfl_xor(ax, 32); ay += __shfl_xor(ay, 32);
    if (g == 0) {
        float d2 = dn * dn;
        float2 hs = *(const float2*)&H2[(size_t)n * NC + l8 * 2];
        float2 bb = *(const float2*)&b2[l8 * 2];
        float vx = ax * dn + hs.x * d2 + bb.x;
        float vy = ay * dn + hs.y * d2 + bb.y;
        float2 o = { 1.0f / (1.0f + expf(-vx)), 1.0f / (1.0f + expf(-vy)) };
        *(float2*)&OUT[(size_t)n * NC + l8 * 2] = o;
    }
}

extern "C" void kernel_launch(void* const* d_in, const int* in_sizes, int n_in,
                              void* d_out, int out_size, void* d_ws, size_t ws_size,
                              hipStream_t stream) {
    const float* X  = (const float*)d_in[0];
    const int*   EI = (const int*)d_in[1];
    const float* W1 = (const float*)d_in[2];
    const float* b1 = (const float*)d_in[3];
    const float* W2 = (const float*)d_in[4];
    const float* b2 = (const float*)d_in[5];
    float* OUT = (float*)d_out;

    const int* src = EI;
    const int* dst = EI + NE;

    // workspace layout (bytes)
    char* ws = (char*)d_ws;
    int*    h       = (int*)(ws);                   // HL ints = 76.8 KB
    int*    hscan   = (int*)(ws + 81920);           // HL+1 ints
    int*    hpart   = (int*)(ws + 163840);          // PB ints
    int*    hpartoff= (int*)(ws + 167936);          // PB ints
    int*    off     = (int*)(ws + 172032);          // NN+1 ints
    float*  dis     = (float*)(ws + 376832);        // NN floats
    __bf16* W1T     = (__bf16*)(ws + 581632);       // 32 KB
    __bf16* W2T     = (__bf16*)(ws + 614400);       // 4 KB
    int*    ebuf    = (int*)(ws + 622592);          // NE int = 3.2 MB
    unsigned short* rec = (unsigned short*)(ws + 3822592);  // NE ushort = 1.6 MB
    __bf16* H1s     = (__bf16*)(ws + 5422592);      // NSL*NN*SW bf16 = 12.8 MB
    __bf16* AGGs    = (__bf16*)(ws + 18222592);     // NSL*NN*SW bf16 = 12.8 MB
    float*  H2      = (float*)(ws + 31022592);      // NN*NC f32 = 3.2 MB

    const int B = 256;

    k_prep<<<(DF * DF + NC * DF + B - 1) / B, B, 0, stream>>>(W1, W2, W1T, W2T);
    k_gemm1_hist<<<GB + HB, B, 0, stream>>>(X, W1T, H1s, dst, h);
    k_hpart<<<PB, B, 0, stream>>>(h, hpart);
    k_hscan_part<<<1, B, 0, stream>>>(hpart, hpartoff, hscan);
    k_hoff<<<PB, B, 0, stream>>>(h, hpartoff, hscan);
    k_scatterA<<<HB, B, 0, stream>>>(src, dst, hscan, ebuf);
    k_rankB<<<NBIN, B, 0, stream>>>(ebuf, hscan, off, dis, rec);

    k_aggS<<<NSL * (NN / 4), B, 0, stream>>>(H1s, dis, off, rec, AGGs);
    k_fin<<<(NN + 3) / 4, B, 0, stream>>>(H1s, AGGs, dis, b1, W2T, H2);
    k_agg2<<<(NN + 3) / 4, B, 0, stream>>>(H2, dis, b2, off, rec, OUT);
}

// Round 13
// 138.079 us; speedup vs baseline: 1.4168x; 1.4168x over previous
//
#include <hip/hip_runtime.h>
#include <math.h>

#define NN 50000
#define NE 800000
#define DF 128
#define NC 16
#define WLD 136            // padded LDS row stride (bf16 elems)
#define NBIN 391           // buckets: bin = dst>>7 (128 nodes per bucket)
#define EPB 8192           // edges per hist/scatter block
#define HB ((NE + EPB - 1) / EPB)      // 98 hist/scatter blocks
#define HL (NBIN * HB)                 // 38318 h entries
#define PB ((HL + 255) / 256)          // 150 scan blocks
#define GB ((NN + 63) / 64)            // 782 gemm1 blocks

typedef __bf16 bf16x8 __attribute__((ext_vector_type(8)));
typedef __bf16 bf16x4 __attribute__((ext_vector_type(4)));
typedef float  f32x4  __attribute__((ext_vector_type(4)));

// ---------------- histogram of dst>>7 per edge block ----------------
__global__ __launch_bounds__(256) void k_hist(const int* __restrict__ dst,
                                              int* __restrict__ h) {
    __shared__ int hc[NBIN];
    const int bb = blockIdx.x, t = threadIdx.x;
    for (int i = t; i < NBIN; i += 256) hc[i] = 0;
    __syncthreads();
    const int base = bb * EPB;
#pragma unroll
    for (int i = 0; i < EPB / 256; ++i) {
        int e = base + i * 256 + t;
        if (e < NE) atomicAdd(&hc[dst[e] >> 7], 1);
    }
    __syncthreads();
    for (int i = t; i < NBIN; i += 256) h[i * HB + bb] = hc[i];   // bin-major
}

// ---------------- scan phase 1: per-block partial sums of h ----------------
__global__ __launch_bounds__(256) void k_hpart(const int* __restrict__ h,
                                               int* __restrict__ part) {
    __shared__ int ws[4];
    const int b = blockIdx.x, t = threadIdx.x;
    const int idx = b * 256 + t;
    int s = (idx < HL) ? h[idx] : 0;
    for (int o = 32; o > 0; o >>= 1) s += __shfl_down(s, o);
    if ((t & 63) == 0) ws[t >> 6] = s;
    __syncthreads();
    if (t == 0) part[b] = ws[0] + ws[1] + ws[2] + ws[3];
}

// ---------------- scan phase 2: scan PB partials (single block) -------------
__global__ __launch_bounds__(256) void k_hscan_part(const int* __restrict__ part,
                                                    int* __restrict__ partoff,
                                                    int* __restrict__ hscan) {
    __shared__ int s[256];
    const int t = threadIdx.x;
    int v = (t < PB) ? part[t] : 0;
    s[t] = v;
    __syncthreads();
    for (int o = 1; o < 256; o <<= 1) {
        int x = (t >= o) ? s[t - o] : 0;
        __syncthreads();
        s[t] += x;
        __syncthreads();
    }
    if (t < PB) partoff[t] = s[t] - v;       // exclusive
    if (t == 255) hscan[HL] = s[255];        // sentinel = NE
}

// ---------------- scan phase 3: block-local scan -> hscan -------------------
__global__ __launch_bounds__(256) void k_hoff(const int* __restrict__ h,
                                              const int* __restrict__ partoff,
                                              int* __restrict__ hscan) {
    __shared__ int s[256];
    const int b = blockIdx.x, t = threadIdx.x;
    const int idx = b * 256 + t;
    int v = (idx < HL) ? h[idx] : 0;
    s[t] = v;
    __syncthreads();
    for (int o = 1; o < 256; o <<= 1) {
        int x = (t >= o) ? s[t - o] : 0;
        __syncthreads();
        s[t] += x;
        __syncthreads();
    }
    if (idx < HL) hscan[idx] = partoff[b] + s[t] - v;
}

// ---------------- fused: [0,GB) gemm1 (MFMA, W1 f32 -> LDS bf16 transposed) |
// ----------------        [GB,GB+HB) scatter into buckets (LDS cursors) ------
__global__ __launch_bounds__(256) void k_gemm1_scatter(const float* __restrict__ X,
                                                       const float* __restrict__ W1,
                                                       __bf16* __restrict__ H1,
                                                       const int* __restrict__ src,
                                                       const int* __restrict__ dst,
                                                       const int* __restrict__ hscan,
                                                       int* __restrict__ ebuf) {
    __shared__ __bf16 wlds[DF * WLD];   // 34 KB
    __shared__ int cur[NBIN];
    if (blockIdx.x >= GB) {
        const int bb = blockIdx.x - GB;
        const int t = threadIdx.x;
        for (int i = t; i < NBIN; i += 256) cur[i] = hscan[i * HB + bb];
        __syncthreads();
        const int base = bb * EPB;
#pragma unroll
        for (int i = 0; i < EPB / 256; ++i) {
            int e = base + i * 256 + t;
            if (e < NE) {
                int s = src[e], d = dst[e];
                int pos = atomicAdd(&cur[d >> 7], 1);
                ebuf[pos] = s | ((d & 127) << 16);
            }
        }
        return;
    }
    const int wid = threadIdx.x >> 6, lane = threadIdx.x & 63;
    const int m0 = blockIdx.x * 64 + wid * 16;
    const int m = m0 + (lane & 15);
    const int mc = (m < NN) ? m : NN - 1;
    const int l15 = lane & 15;
    const int kb = (lane >> 4) * 8;

    // prefetch all 8 X float4 chunks (independent, in flight together)
    float4 xf[8];
#pragma unroll
    for (int q = 0; q < 4; ++q) {
        xf[2 * q]     = *(const float4*)&X[(size_t)mc * DF + q * 32 + kb];
        xf[2 * q + 1] = *(const float4*)&X[(size_t)mc * DF + q * 32 + kb + 4];
    }
    // transpose W1 (f32, [k][n]) -> wlds[n][k] bf16 (one-time staging)
    for (int i = threadIdx.x; i < DF * DF; i += 256) {
        int k = i >> 7, n = i & 127;
        wlds[n * WLD + k] = (__bf16)W1[i];
    }
    __syncthreads();

    f32x4 acc[8];
#pragma unroll
    for (int nf = 0; nf < 8; ++nf) acc[nf] = (f32x4){0.f, 0.f, 0.f, 0.f};
#pragma unroll
    for (int ks = 0; ks < 4; ++ks) {
        float4 x0 = xf[2 * ks], x1 = xf[2 * ks + 1];
        bf16x8 xa;
        xa[0] = (__bf16)x0.x; xa[1] = (__bf16)x0.y; xa[2] = (__bf16)x0.z; xa[3] = (__bf16)x0.w;
        xa[4] = (__bf16)x1.x; xa[5] = (__bf16)x1.y; xa[6] = (__bf16)x1.z; xa[7] = (__bf16)x1.w;
#pragma unroll
        for (int nf = 0; nf < 8; ++nf) {
            bf16x8 wa = *(const bf16x8*)&wlds[(nf * 16 + l15) * WLD + ks * 32 + kb];
            acc[nf] = __builtin_amdgcn_mfma_f32_16x16x32_bf16(wa, xa, acc[nf], 0, 0, 0);
        }
    }
    if (m < NN) {
#pragma unroll
        for (int nf = 0; nf < 8; ++nf) {
            bf16x4 o;
            o[0] = (__bf16)acc[nf][0]; o[1] = (__bf16)acc[nf][1];
            o[2] = (__bf16)acc[nf][2]; o[3] = (__bf16)acc[nf][3];
            *(bf16x4*)&H1[(size_t)m * DF + nf * 16 + (lane >> 4) * 4] = o;
        }
    }
}

// ---------------- per-bucket rank (128 nodes): off, dis, rec[src] -----------
__global__ __launch_bounds__(256) void k_rankB(const int* __restrict__ ebuf,
                                               const int* __restrict__ hscan,
                                               int* __restrict__ off,
                                               float* __restrict__ dis,
                                               unsigned short* __restrict__ rec) {
    __shared__ int cnt[128], s[256], cur[128];
    const int bin = blockIdx.x, t = threadIdx.x;
    const int base = hscan[bin * HB];
    const int end  = hscan[(bin + 1) * HB];   // bin+1==NBIN -> sentinel = NE
    if (t < 128) cnt[t] = 0;
    __syncthreads();
    for (int e = base + t; e < end; e += 256)
        atomicAdd(&cnt[(ebuf[e] >> 16) & 127], 1);
    __syncthreads();
    int c = (t < 128) ? cnt[t] : 0;
    s[t] = c;
    __syncthreads();
    for (int o = 1; o < 256; o <<= 1) {
        int x = (t >= o) ? s[t - o] : 0;
        __syncthreads();
        s[t] += x;
        __syncthreads();
    }
    int lo = s[t] - c;                         // exclusive within bucket
    int d = (bin << 7) + t;
    if (t < 128 && d < NN) {
        off[d] = base + lo;
        dis[d] = rsqrtf((float)(c + 1));       // +1 self-loop
    }
    if (bin == NBIN - 1 && t == 0) off[NN] = NE;
    if (t < 128) cur[t] = base + lo;
    __syncthreads();
    for (int e = base + t; e < end; e += 256) {
        int ed = ebuf[e];
        int p = atomicAdd(&cur[(ed >> 16) & 127], 1);
        rec[p] = (unsigned short)(ed & 0xFFFF);
    }
}

// ---------------- agg1 + gemm2 fused: one node per wave, unroll-4 -----------
__global__ __launch_bounds__(256) void k_agg1g2(const __bf16* __restrict__ H1,
                                                const float* __restrict__ dis,
                                                const float* __restrict__ b1,
                                                const float* __restrict__ W2,
                                                const int* __restrict__ off,
                                                const unsigned short* __restrict__ rec,
                                                float* __restrict__ H2) {
    const int wid = threadIdx.x >> 6, lane = threadIdx.x & 63;
    const int n = blockIdx.x * 4 + wid;
    if (n >= NN) return;
    const int g = lane >> 4, l16 = lane & 15;
    const int fo = l16 * 8;
    const float dn = dis[n];

    float a[8];
#pragma unroll
    for (int i = 0; i < 8; ++i) a[i] = 0.f;

    const int e0 = off[n], e1 = off[n + 1];
    int e = e0 + g;
    // 4 edges in flight per 16-lane group (16 rows in flight per wave)
    for (; e + 12 < e1; e += 16) {
        int r0 = rec[e];
        int r1 = rec[e + 4];
        int r2 = rec[e + 8];
        int r3 = rec[e + 12];
        float w0 = dis[r0], w1 = dis[r1], w2 = dis[r2], w3 = dis[r3];
        bf16x8 h0 = *(const bf16x8*)&H1[(size_t)r0 * DF + fo];
        bf16x8 h1 = *(const bf16x8*)&H1[(size_t)r1 * DF + fo];
        bf16x8 h2 = *(const bf16x8*)&H1[(size_t)r2 * DF + fo];
        bf16x8 h3 = *(const bf16x8*)&H1[(size_t)r3 * DF + fo];
#pragma unroll
        for (int i = 0; i < 8; ++i) a[i] += (float)h0[i] * w0;
#pragma unroll
        for (int i = 0; i < 8; ++i) a[i] += (float)h1[i] * w1;
#pragma unroll
        for (int i = 0; i < 8; ++i) a[i] += (float)h2[i] * w2;
#pragma unroll
        for (int i = 0; i < 8; ++i) a[i] += (float)h3[i] * w3;
    }
    for (; e < e1; e += 4) {
        int r = rec[e];
        float w = dis[r];
        bf16x8 h = *(const bf16x8*)&H1[(size_t)r * DF + fo];
#pragma unroll
        for (int i = 0; i < 8; ++i) a[i] += (float)h[i] * w;
    }
#pragma unroll
    for (int i = 0; i < 8; ++i) {
        a[i] += __shfl_xor(a[i], 16);
        a[i] += __shfl_xor(a[i], 32);
    }
    // finalize on ALL lanes: a = relu(edge_sum*dn + self*dn^2 + bias)
    {
        const float d2 = dn * dn;
        float4 b0 = *(const float4*)&b1[fo];
        float4 b4 = *(const float4*)&b1[fo + 4];
        bf16x8 hs = *(const bf16x8*)&H1[(size_t)n * DF + fo];
        a[0] = fmaxf(a[0] * dn + (float)hs[0] * d2 + b0.x, 0.f);
        a[1] = fmaxf(a[1] * dn + (float)hs[1] * d2 + b0.y, 0.f);
        a[2] = fmaxf(a[2] * dn + (float)hs[2] * d2 + b0.z, 0.f);
        a[3] = fmaxf(a[3] * dn + (float)hs[3] * d2 + b0.w, 0.f);
        a[4] = fmaxf(a[4] * dn + (float)hs[4] * d2 + b4.x, 0.f);
        a[5] = fmaxf(a[5] * dn + (float)hs[5] * d2 + b4.y, 0.f);
        a[6] = fmaxf(a[6] * dn + (float)hs[6] * d2 + b4.z, 0.f);
        a[7] = fmaxf(a[7] * dn + (float)hs[7] * d2 + b4.w, 0.f);
    }

    // mini-GEMM: lane computes 4 classes (g*4..g*4+3) over its 8 feats,
    // reading W2 (f32, row-major [k][c], 8 KB -> L2-resident) directly
    float p[4] = {0.f, 0.f, 0.f, 0.f};
#pragma unroll
    for (int i = 0; i < 8; ++i) {
        float4 wv = *(const float4*)&W2[(size_t)(fo + i) * NC + g * 4];
        p[0] += a[i] * wv.x;
        p[1] += a[i] * wv.y;
        p[2] += a[i] * wv.z;
        p[3] += a[i] * wv.w;
    }
#pragma unroll
    for (int o = 1; o <= 8; o <<= 1) {
#pragma unroll
        for (int j = 0; j < 4; ++j) p[j] += __shfl_xor(p[j], o);
    }
    if (l16 == 0) {
        f32x4 o4 = {p[0], p[1], p[2], p[3]};
        *(f32x4*)&H2[(size_t)n * NC + g * 4] = o4;
    }
}

// ---------------- agg layer 2: unroll-2, fused sigmoid -> OUT ---------------
__global__ __launch_bounds__(256) void k_agg2(const float* __restrict__ H2,
                                              const float* __restrict__ dis,
                                              const float* __restrict__ b2,
                                              const int* __restrict__ off,
                                              const unsigned short* __restrict__ rec,
                                              float* __restrict__ OUT) {
    const int wid = threadIdx.x >> 6, lane = threadIdx.x & 63;
    const int n = blockIdx.x * 4 + wid;
    if (n >= NN) return;
    const float dn = dis[n];

    const int g = lane >> 3, l8 = lane & 7;
    float ax = 0.f, ay = 0.f;
    const int e0 = off[n], e1 = off[n + 1];
    int e = e0 + g;
    for (; e + 8 < e1; e += 16) {
        int r0 = rec[e];
        int r1 = rec[e + 8];
        float w0 = dis[r0], w1 = dis[r1];
        float2 h0 = *(const float2*)&H2[(size_t)r0 * NC + l8 * 2];
        float2 h1 = *(const float2*)&H2[(size_t)r1 * NC + l8 * 2];
        ax += h0.x * w0;
        ay += h0.y * w0;
        ax += h1.x * w1;
        ay += h1.y * w1;
    }
    for (; e < e1; e += 8) {
        int r = rec[e];
        float w = dis[r];
        float2 h = *(const float2*)&H2[(size_t)r * NC + l8 * 2];
        ax += h.x * w;
        ay += h.y * w;
    }
    ax += __shfl_xor(ax, 8);  ay += __shfl_xor(ay, 8);
    ax += __shfl_xor(ax, 16); ay += __shfl_xor(ay, 16);
    ax += __shfl_xor(ax, 32); ay += __shfl_xor(ay, 32);
    if (g == 0) {
        float d2 = dn * dn;
        float2 hs = *(const float2*)&H2[(size_t)n * NC + l8 * 2];
        float2 bb = *(const float2*)&b2[l8 * 2];
        float vx = ax * dn + hs.x * d2 + bb.x;
        float vy = ay * dn + hs.y * d2 + bb.y;
        float2 o = { 1.0f / (1.0f + expf(-vx)), 1.0f / (1.0f + expf(-vy)) };
        *(float2*)&OUT[(size_t)n * NC + l8 * 2] = o;
    }
}

extern "C" void kernel_launch(void* const* d_in, const int* in_sizes, int n_in,
                              void* d_out, int out_size, void* d_ws, size_t ws_size,
                              hipStream_t stream) {
    const float* X  = (const float*)d_in[0];
    const int*   EI = (const int*)d_in[1];
    const float* W1 = (const float*)d_in[2];
    const float* b1 = (const float*)d_in[3];
    const float* W2 = (const float*)d_in[4];
    const float* b2 = (const float*)d_in[5];
    float* OUT = (float*)d_out;

    const int* src = EI;
    const int* dst = EI + NE;

    // workspace layout (bytes)
    char* ws = (char*)d_ws;
    int*    h       = (int*)(ws);                   // HL ints = 153.3 KB
    int*    hscan   = (int*)(ws + 163840);          // HL+1 ints
    int*    hpart   = (int*)(ws + 327680);          // PB ints
    int*    hpartoff= (int*)(ws + 331776);          // PB ints
    int*    off     = (int*)(ws + 335872);          // NN+1 ints
    float*  dis     = (float*)(ws + 540672);        // NN floats
    int*    ebuf    = (int*)(ws + 745472);          // NE int = 3.2 MB
    unsigned short* rec = (unsigned short*)(ws + 3945472);  // NE ushort = 1.6 MB
    __bf16* H1      = (__bf16*)(ws + 5545472);      // NN*DF bf16 = 12.8 MB
    float*  H2      = (float*)(ws + 18345472);      // NN*NC f32 = 3.2 MB

    const int B = 256;

    k_hist<<<HB, B, 0, stream>>>(dst, h);
    k_hpart<<<PB, B, 0, stream>>>(h, hpart);
    k_hscan_part<<<1, B, 0, stream>>>(hpart, hpartoff, hscan);
    k_hoff<<<PB, B, 0, stream>>>(h, hpartoff, hscan);
    k_gemm1_scatter<<<GB + HB, B, 0, stream>>>(X, W1, H1, src, dst, hscan, ebuf);
    k_rankB<<<NBIN, B, 0, stream>>>(ebuf, hscan, off, dis, rec);

    k_agg1g2<<<(NN + 3) / 4, B, 0, stream>>>(H1, dis, b1, W2, off, rec, H2);
    k_agg2<<<(NN + 3) / 4, B, 0, stream>>>(H2, dis, b2, off, rec, OUT);
}

// Round 14
// 104.471 us; speedup vs baseline: 1.8725x; 1.3217x over previous
//
#include <hip/hip_runtime.h>
#include <math.h>

#define NN 50000
#define NE 800000
#define DF 128
#define NC 16
#define WLD 136            // padded LDS row stride (bf16 elems)
#define NBIN 391           // buckets: bin = dst>>7 (128 nodes per bucket)
#define EPB 8192           // edges per hist/scatter block
#define HB ((NE + EPB - 1) / EPB)      // 98 hist/scatter blocks
#define HL (NBIN * HB)                 // 38318 h entries
#define PB ((HL + 255) / 256)          // 150 scan blocks
#define GB ((NN + 63) / 64)            // 782 gemm1 blocks

typedef __bf16 bf16x8 __attribute__((ext_vector_type(8)));
typedef __bf16 bf16x4 __attribute__((ext_vector_type(4)));
typedef __bf16 bf16x2 __attribute__((ext_vector_type(2)));
typedef float  f32x4  __attribute__((ext_vector_type(4)));
typedef float  f32x2  __attribute__((ext_vector_type(2)));

// ---------------- histogram of dst>>7 per edge block ----------------
__global__ __launch_bounds__(256) void k_hist(const int* __restrict__ dst,
                                              int* __restrict__ h) {
    __shared__ int hc[NBIN];
    const int bb = blockIdx.x, t = threadIdx.x;
    for (int i = t; i < NBIN; i += 256) hc[i] = 0;
    __syncthreads();
    const int base = bb * EPB;
#pragma unroll
    for (int i = 0; i < EPB / 256; ++i) {
        int e = base + i * 256 + t;
        if (e < NE) atomicAdd(&hc[dst[e] >> 7], 1);
    }
    __syncthreads();
    for (int i = t; i < NBIN; i += 256) h[i * HB + bb] = hc[i];   // bin-major
}

// ---------------- scan phase 1: per-block partial sums of h ----------------
__global__ __launch_bounds__(256) void k_hpart(const int* __restrict__ h,
                                               int* __restrict__ part) {
    __shared__ int ws[4];
    const int b = blockIdx.x, t = threadIdx.x;
    const int idx = b * 256 + t;
    int s = (idx < HL) ? h[idx] : 0;
    for (int o = 32; o > 0; o >>= 1) s += __shfl_down(s, o);
    if ((t & 63) == 0) ws[t >> 6] = s;
    __syncthreads();
    if (t == 0) part[b] = ws[0] + ws[1] + ws[2] + ws[3];
}

// ---------------- scan phase 2: scan PB partials + W2->W2T conversion -------
__global__ __launch_bounds__(256) void k_hscan_part(const int* __restrict__ part,
                                                    int* __restrict__ partoff,
                                                    int* __restrict__ hscan,
                                                    const float* __restrict__ W2,
                                                    __bf16* __restrict__ W2T) {
    __shared__ int s[256];
    const int t = threadIdx.x;
    // fused W2T conversion (block is otherwise mostly idle)
    for (int i = t; i < NC * DF; i += 256) {
        int n = i >> 7, k = i & 127;
        W2T[i] = (__bf16)W2[k * NC + n];
    }
    int v = (t < PB) ? part[t] : 0;
    s[t] = v;
    __syncthreads();
    for (int o = 1; o < 256; o <<= 1) {
        int x = (t >= o) ? s[t - o] : 0;
        __syncthreads();
        s[t] += x;
        __syncthreads();
    }
    if (t < PB) partoff[t] = s[t] - v;       // exclusive
    if (t == 255) hscan[HL] = s[255];        // sentinel = NE
}

// ---------------- scan phase 3: block-local scan -> hscan -------------------
__global__ __launch_bounds__(256) void k_hoff(const int* __restrict__ h,
                                              const int* __restrict__ partoff,
                                              int* __restrict__ hscan) {
    __shared__ int s[256];
    const int b = blockIdx.x, t = threadIdx.x;
    const int idx = b * 256 + t;
    int v = (idx < HL) ? h[idx] : 0;
    s[t] = v;
    __syncthreads();
    for (int o = 1; o < 256; o <<= 1) {
        int x = (t >= o) ? s[t - o] : 0;
        __syncthreads();
        s[t] += x;
        __syncthreads();
    }
    if (idx < HL) hscan[idx] = partoff[b] + s[t] - v;
}

// ---------------- fused: [0,GB) gemm1 (MFMA, W1 f32 -> LDS bf16, fp8 out) |
// ----------------        [GB,GB+HB) scatter into buckets (LDS cursors) ------
__global__ __launch_bounds__(256) void k_gemm1_scatter(const float* __restrict__ X,
                                                       const float* __restrict__ W1,
                                                       unsigned char* __restrict__ H1,
                                                       const int* __restrict__ src,
                                                       const int* __restrict__ dst,
                                                       const int* __restrict__ hscan,
                                                       int* __restrict__ ebuf) {
    __shared__ __bf16 wlds[DF * WLD];   // 34 KB
    __shared__ int cur[NBIN];
    if (blockIdx.x >= GB) {
        const int bb = blockIdx.x - GB;
        const int t = threadIdx.x;
        for (int i = t; i < NBIN; i += 256) cur[i] = hscan[i * HB + bb];
        __syncthreads();
        const int base = bb * EPB;
#pragma unroll
        for (int i = 0; i < EPB / 256; ++i) {
            int e = base + i * 256 + t;
            if (e < NE) {
                int s = src[e], d = dst[e];
                int pos = atomicAdd(&cur[d >> 7], 1);
                ebuf[pos] = s | ((d & 127) << 16);
            }
        }
        return;
    }
    const int wid = threadIdx.x >> 6, lane = threadIdx.x & 63;
    const int m0 = blockIdx.x * 64 + wid * 16;
    const int m = m0 + (lane & 15);
    const int mc = (m < NN) ? m : NN - 1;
    const int l15 = lane & 15;
    const int kb = (lane >> 4) * 8;

    // prefetch all 8 X float4 chunks (independent, in flight together)
    float4 xf[8];
#pragma unroll
    for (int q = 0; q < 4; ++q) {
        xf[2 * q]     = *(const float4*)&X[(size_t)mc * DF + q * 32 + kb];
        xf[2 * q + 1] = *(const float4*)&X[(size_t)mc * DF + q * 32 + kb + 4];
    }
    // transpose W1 (f32, [k][n]) -> wlds[n][k] bf16 (one-time staging)
    for (int i = threadIdx.x; i < DF * DF; i += 256) {
        int k = i >> 7, n = i & 127;
        wlds[n * WLD + k] = (__bf16)W1[i];
    }
    __syncthreads();

    f32x4 acc[8];
#pragma unroll
    for (int nf = 0; nf < 8; ++nf) acc[nf] = (f32x4){0.f, 0.f, 0.f, 0.f};
#pragma unroll
    for (int ks = 0; ks < 4; ++ks) {
        float4 x0 = xf[2 * ks], x1 = xf[2 * ks + 1];
        bf16x8 xa;
        xa[0] = (__bf16)x0.x; xa[1] = (__bf16)x0.y; xa[2] = (__bf16)x0.z; xa[3] = (__bf16)x0.w;
        xa[4] = (__bf16)x1.x; xa[5] = (__bf16)x1.y; xa[6] = (__bf16)x1.z; xa[7] = (__bf16)x1.w;
#pragma unroll
        for (int nf = 0; nf < 8; ++nf) {
            bf16x8 wa = *(const bf16x8*)&wlds[(nf * 16 + l15) * WLD + ks * 32 + kb];
            acc[nf] = __builtin_amdgcn_mfma_f32_16x16x32_bf16(wa, xa, acc[nf], 0, 0, 0);
        }
    }
    if (m < NN) {
#pragma unroll
        for (int nf = 0; nf < 8; ++nf) {   // pack 4 f32 -> 4 fp8 e4m3 bytes
            int pw = __builtin_amdgcn_cvt_pk_fp8_f32(acc[nf][0], acc[nf][1], 0, false);
            pw = __builtin_amdgcn_cvt_pk_fp8_f32(acc[nf][2], acc[nf][3], pw, true);
            *(unsigned int*)&H1[(size_t)m * DF + nf * 16 + (lane >> 4) * 4] = (unsigned int)pw;
        }
    }
}

// ---------------- per-bucket rank (128 nodes): off, dis, rec[src] -----------
__global__ __launch_bounds__(256) void k_rankB(const int* __restrict__ ebuf,
                                               const int* __restrict__ hscan,
                                               int* __restrict__ off,
                                               float* __restrict__ dis,
                                               unsigned short* __restrict__ rec) {
    __shared__ int cnt[128], s[256], cur[128];
    const int bin = blockIdx.x, t = threadIdx.x;
    const int base = hscan[bin * HB];
    const int end  = hscan[(bin + 1) * HB];   // bin+1==NBIN -> sentinel = NE
    if (t < 128) cnt[t] = 0;
    __syncthreads();
    for (int e = base + t; e < end; e += 256)
        atomicAdd(&cnt[(ebuf[e] >> 16) & 127], 1);
    __syncthreads();
    int c = (t < 128) ? cnt[t] : 0;
    s[t] = c;
    __syncthreads();
    for (int o = 1; o < 256; o <<= 1) {
        int x = (t >= o) ? s[t - o] : 0;
        __syncthreads();
        s[t] += x;
        __syncthreads();
    }
    int lo = s[t] - c;                         // exclusive within bucket
    int d = (bin << 7) + t;
    if (t < 128 && d < NN) {
        off[d] = base + lo;
        dis[d] = rsqrtf((float)(c + 1));       // +1 self-loop
    }
    if (bin == NBIN - 1 && t == 0) off[NN] = NE;
    if (t < 128) cur[t] = base + lo;
    __syncthreads();
    for (int e = base + t; e < end; e += 256) {
        int ed = ebuf[e];
        int p = atomicAdd(&cur[(ed >> 16) & 127], 1);
        rec[p] = (unsigned short)(ed & 0xFFFF);
    }
}

// ---------------- agg1 + gemm2 fused: one node per wave, unroll-4, fp8 H1 ---
__global__ __launch_bounds__(256) void k_agg1g2(const unsigned char* __restrict__ H1,
                                                const float* __restrict__ dis,
                                                const float* __restrict__ b1,
                                                const __bf16* __restrict__ W2T,
                                                const int* __restrict__ off,
                                                const unsigned short* __restrict__ rec,
                                                __bf16* __restrict__ H2) {
    const int wid = threadIdx.x >> 6, lane = threadIdx.x & 63;
    const int n = blockIdx.x * 4 + wid;
    if (n >= NN) return;
    const int g = lane >> 4, l16 = lane & 15;
    const int fo = l16 * 8;                    // feat (and byte) offset
    const float dn = dis[n];

    float a[8];
#pragma unroll
    for (int i = 0; i < 8; ++i) a[i] = 0.f;

    const int e0 = off[n], e1 = off[n + 1];
    int e = e0 + g;
    // 4 edges in flight per 16-lane group (16 rows in flight per wave)
    for (; e + 12 < e1; e += 16) {
        int r0 = rec[e];
        int r1 = rec[e + 4];
        int r2 = rec[e + 8];
        int r3 = rec[e + 12];
        float w0 = dis[r0], w1 = dis[r1], w2 = dis[r2], w3 = dis[r3];
        uint2 u0 = *(const uint2*)&H1[(size_t)r0 * DF + fo];
        uint2 u1 = *(const uint2*)&H1[(size_t)r1 * DF + fo];
        uint2 u2 = *(const uint2*)&H1[(size_t)r2 * DF + fo];
        uint2 u3 = *(const uint2*)&H1[(size_t)r3 * DF + fo];
#define ACC8(u, w)                                                        \
        {                                                                 \
            f32x2 p0 = __builtin_amdgcn_cvt_pk_f32_fp8((u).x, false);     \
            f32x2 p1 = __builtin_amdgcn_cvt_pk_f32_fp8((u).x, true);      \
            f32x2 p2 = __builtin_amdgcn_cvt_pk_f32_fp8((u).y, false);     \
            f32x2 p3 = __builtin_amdgcn_cvt_pk_f32_fp8((u).y, true);      \
            a[0] += p0[0] * (w); a[1] += p0[1] * (w);                     \
            a[2] += p1[0] * (w); a[3] += p1[1] * (w);                     \
            a[4] += p2[0] * (w); a[5] += p2[1] * (w);                     \
            a[6] += p3[0] * (w); a[7] += p3[1] * (w);                     \
        }
        ACC8(u0, w0) ACC8(u1, w1) ACC8(u2, w2) ACC8(u3, w3)
    }
    for (; e < e1; e += 4) {
        int r = rec[e];
        float w = dis[r];
        uint2 u = *(const uint2*)&H1[(size_t)r * DF + fo];
        ACC8(u, w)
    }
#undef ACC8
#pragma unroll
    for (int i = 0; i < 8; ++i) {
        a[i] += __shfl_xor(a[i], 16);
        a[i] += __shfl_xor(a[i], 32);
    }
    // finalize on ALL lanes: a = relu(edge_sum*dn + self*dn^2 + bias)
    {
        const float d2 = dn * dn;
        float4 b0 = *(const float4*)&b1[fo];
        float4 b4 = *(const float4*)&b1[fo + 4];
        uint2 us = *(const uint2*)&H1[(size_t)n * DF + fo];
        f32x2 s0 = __builtin_amdgcn_cvt_pk_f32_fp8(us.x, false);
        f32x2 s1 = __builtin_amdgcn_cvt_pk_f32_fp8(us.x, true);
        f32x2 s2 = __builtin_amdgcn_cvt_pk_f32_fp8(us.y, false);
        f32x2 s3 = __builtin_amdgcn_cvt_pk_f32_fp8(us.y, true);
        a[0] = fmaxf(a[0] * dn + s0[0] * d2 + b0.x, 0.f);
        a[1] = fmaxf(a[1] * dn + s0[1] * d2 + b0.y, 0.f);
        a[2] = fmaxf(a[2] * dn + s1[0] * d2 + b0.z, 0.f);
        a[3] = fmaxf(a[3] * dn + s1[1] * d2 + b0.w, 0.f);
        a[4] = fmaxf(a[4] * dn + s2[0] * d2 + b4.x, 0.f);
        a[5] = fmaxf(a[5] * dn + s2[1] * d2 + b4.y, 0.f);
        a[6] = fmaxf(a[6] * dn + s3[0] * d2 + b4.z, 0.f);
        a[7] = fmaxf(a[7] * dn + s3[1] * d2 + b4.w, 0.f);
    }

    // mini-GEMM: lane computes 4 classes (g*4..g*4+3) over its 8 feats
    float p[4];
#pragma unroll
    for (int j = 0; j < 4; ++j) {
        bf16x8 wr = *(const bf16x8*)&W2T[(size_t)(g * 4 + j) * DF + fo];
        float s = 0.f;
#pragma unroll
        for (int i = 0; i < 8; ++i) s += a[i] * (float)wr[i];
        p[j] = s;
    }
#pragma unroll
    for (int o = 1; o <= 8; o <<= 1) {
#pragma unroll
        for (int j = 0; j < 4; ++j) p[j] += __shfl_xor(p[j], o);
    }
    if (l16 == 0) {
        bf16x4 o4;
        o4[0] = (__bf16)p[0]; o4[1] = (__bf16)p[1];
        o4[2] = (__bf16)p[2]; o4[3] = (__bf16)p[3];
        *(bf16x4*)&H2[(size_t)n * NC + g * 4] = o4;
    }
}

// ---------------- agg layer 2: unroll-2, bf16 H2, fused sigmoid -> OUT ------
__global__ __launch_bounds__(256) void k_agg2(const __bf16* __restrict__ H2,
                                              const float* __restrict__ dis,
                                              const float* __restrict__ b2,
                                              const int* __restrict__ off,
                                              const unsigned short* __restrict__ rec,
                                              float* __restrict__ OUT) {
    const int wid = threadIdx.x >> 6, lane = threadIdx.x & 63;
    const int n = blockIdx.x * 4 + wid;
    if (n >= NN) return;
    const float dn = dis[n];

    const int g = lane >> 3, l8 = lane & 7;
    float ax = 0.f, ay = 0.f;
    const int e0 = off[n], e1 = off[n + 1];
    int e = e0 + g;
    for (; e + 8 < e1; e += 16) {
        int r0 = rec[e];
        int r1 = rec[e + 8];
        float w0 = dis[r0], w1 = dis[r1];
        bf16x2 h0 = *(const bf16x2*)&H2[(size_t)r0 * NC + l8 * 2];
        bf16x2 h1 = *(const bf16x2*)&H2[(size_t)r1 * NC + l8 * 2];
        ax += (float)h0[0] * w0;
        ay += (float)h0[1] * w0;
        ax += (float)h1[0] * w1;
        ay += (float)h1[1] * w1;
    }
    for (; e < e1; e += 8) {
        int r = rec[e];
        float w = dis[r];
        bf16x2 h = *(const bf16x2*)&H2[(size_t)r * NC + l8 * 2];
        ax += (float)h[0] * w;
        ay += (float)h[1] * w;
    }
    ax += __shfl_xor(ax, 8);  ay += __shfl_xor(ay, 8);
    ax += __shfl_xor(ax, 16); ay += __shfl_xor(ay, 16);
    ax += __shfl_xor(ax, 32); ay += __shfl_xor(ay, 32);
    if (g == 0) {
        float d2 = dn * dn;
        bf16x2 hs = *(const bf16x2*)&H2[(size_t)n * NC + l8 * 2];
        float2 bb = *(const float2*)&b2[l8 * 2];
        float vx = ax * dn + (float)hs[0] * d2 + bb.x;
        float vy = ay * dn + (float)hs[1] * d2 + bb.y;
        float2 o = { 1.0f / (1.0f + expf(-vx)), 1.0f / (1.0f + expf(-vy)) };
        *(float2*)&OUT[(size_t)n * NC + l8 * 2] = o;
    }
}

extern "C" void kernel_launch(void* const* d_in, const int* in_sizes, int n_in,
                              void* d_out, int out_size, void* d_ws, size_t ws_size,
                              hipStream_t stream) {
    const float* X  = (const float*)d_in[0];
    const int*   EI = (const int*)d_in[1];
    const float* W1 = (const float*)d_in[2];
    const float* b1 = (const float*)d_in[3];
    const float* W2 = (const float*)d_in[4];
    const float* b2 = (const float*)d_in[5];
    float* OUT = (float*)d_out;

    const int* src = EI;
    const int* dst = EI + NE;

    // workspace layout (bytes)
    char* ws = (char*)d_ws;
    int*    h       = (int*)(ws);                   // HL ints = 153.3 KB
    int*    hscan   = (int*)(ws + 163840);          // HL+1 ints
    int*    hpart   = (int*)(ws + 327680);          // PB ints
    int*    hpartoff= (int*)(ws + 331776);          // PB ints
    int*    off     = (int*)(ws + 335872);          // NN+1 ints
    float*  dis     = (float*)(ws + 540672);        // NN floats
    __bf16* W2T     = (__bf16*)(ws + 745472);       // 4 KB
    int*    ebuf    = (int*)(ws + 749568);          // NE int = 3.2 MB
    unsigned short* rec = (unsigned short*)(ws + 3949568);  // NE ushort = 1.6 MB
    unsigned char* H1 = (unsigned char*)(ws + 5549568);     // NN*DF fp8 = 6.4 MB
    __bf16* H2      = (__bf16*)(ws + 11949568);     // NN*NC bf16 = 1.6 MB

    const int B = 256;

    k_hist<<<HB, B, 0, stream>>>(dst, h);
    k_hpart<<<PB, B, 0, stream>>>(h, hpart);
    k_hscan_part<<<1, B, 0, stream>>>(hpart, hpartoff, hscan, W2, W2T);
    k_hoff<<<PB, B, 0, stream>>>(h, hpartoff, hscan);
    k_gemm1_scatter<<<GB + HB, B, 0, stream>>>(X, W1, H1, src, dst, hscan, ebuf);
    k_rankB<<<NBIN, B, 0, stream>>>(ebuf, hscan, off, dis, rec);

    k_agg1g2<<<(NN + 3) / 4, B, 0, stream>>>(H1, dis, b1, W2T, off, rec, H2);
    k_agg2<<<(NN + 3) / 4, B, 0, stream>>>(H2, dis, b2, off, rec, OUT);
}